// Round 7
// baseline (429.905 us; speedup 1.0000x reference)
//
#include <hip/hip_runtime.h>
#include <hip/hip_bf16.h>
#include <stdint.h>

#define DM   1024
#define DI   2048
#define NST  16
#define BSZ  4
#define SLEN 2048
#define MROWS (BSZ*SLEN)   // 8192
#define CHUNK 32
#define NCH  (SLEN/CHUNK)  // 64
#define DECAYF 0.95f
#define MB (size_t)1048576

typedef _Float16 f16;
typedef __attribute__((ext_vector_type(2))) _Float16 f16x2;
typedef __attribute__((ext_vector_type(4))) _Float16 f16x4;
typedef __attribute__((ext_vector_type(8))) _Float16 f16x8;
typedef __attribute__((ext_vector_type(4))) float f32x4;

__device__ __forceinline__ float silu_f(float v) { return v / (1.f + __expf(-v)); }

__device__ __forceinline__ void gload16(const f16* lds, const f16* g) {
  __builtin_amdgcn_global_load_lds((const __attribute__((address_space(1))) void*)g,
                                   (__attribute__((address_space(3))) void*)lds, 16, 0, 0);
}

// ---- fused preprocessing: x->A1 f16, W_in->B1 f16, W_out->W2 f16, B_log->expBT ----
#define NX4  (MROWS * DM / 4)          // 2,097,152
#define NWI4 (2 * DI * DM / 4)         // 1,048,576
#define NWO4 (DM * DI / 4)             // 524,288
#define NE4  (NST * DI / 4)            // 8,192
__global__ __launch_bounds__(256) void cvt_all(
    const float* __restrict__ x, const float* __restrict__ wi, const float* __restrict__ wo,
    const float* __restrict__ B_log,
    f16* __restrict__ A1, f16* __restrict__ B1, f16* __restrict__ W2, float* __restrict__ expBT)
{
  int i = blockIdx.x * 256 + threadIdx.x;
  if (i < NX4 + NWI4 + NWO4) {
    const float* src; f16* dst; int j;
    if (i < NX4)              { src = x;  dst = A1; j = i; }
    else if (i < NX4 + NWI4)  { src = wi; dst = B1; j = i - NX4; }
    else                      { src = wo; dst = W2; j = i - NX4 - NWI4; }
    float4 v = ((const float4*)src)[j];
    f16x4 o = {(f16)v.x, (f16)v.y, (f16)v.z, (f16)v.w};
    ((f16x4*)dst)[j] = o;
  } else {
    int j = i - NX4 - NWI4 - NWO4;     // [0, NE4)
    int base = j * 4;                  // element index n*DI+d
    int n = base >> 11, d = base & (DI - 1);
    float4 o = {__expf(B_log[(d + 0) * NST + n]), __expf(B_log[(d + 1) * NST + n]),
                __expf(B_log[(d + 2) * NST + n]), __expf(B_log[(d + 3) * NST + n])};
    ((float4*)expBT)[j] = o;
  }
}

// ---------------- fp16 MFMA GEMM, BK=64, XOR-swizzled LDS, LDS-staged f16 epilogue ----------
// MODE 1: cols < DI -> O0 = Xi (f16), cols >= DI -> O1 = Z raw (f16). MODE 0: O0 = G (f16).
template<int MODE>
__global__ __launch_bounds__(256) void gemm_bt(
    const f16* __restrict__ A, const f16* __restrict__ Bt,
    int K, f16* __restrict__ O0, f16* __restrict__ O1)
{
  __shared__ __align__(16) f16 sA[128 * 64];
  __shared__ __align__(16) f16 sB[128 * 64];
  const int tid  = threadIdx.x;
  const int lane = tid & 63;
  const int w    = tid >> 6;
  const int wr   = w >> 1, wc = w & 1;

  // bijective XCD swizzle (nwg % 8 == 0 for both GEMMs)
  const int nwg  = gridDim.x * gridDim.y;
  int wgid = blockIdx.y * gridDim.x + blockIdx.x;
  wgid = (wgid & 7) * (nwg >> 3) + (wgid >> 3);
  const int bx = wgid % gridDim.x;
  const int by = wgid / gridDim.x;

  const int mBase = by * 128;
  const int nBase = bx * 128;
  const int lr = lane & 15;
  const int lu = lane >> 4;   // k-unit (8 f16) within 32-k window

  f32x4 acc[4][4];
  #pragma unroll
  for (int m = 0; m < 4; ++m)
    #pragma unroll
    for (int n = 0; n < 4; ++n)
      acc[m][n] = (f32x4){0.f, 0.f, 0.f, 0.f};

  // ds_read offsets (f16 units), loop-invariant
  int offA[4][2], offB[4][2];
  #pragma unroll
  for (int m = 0; m < 4; ++m) {
    int ra = wr * 64 + m * 16 + lr;
    int rb = wc * 64 + m * 16 + lr;
    #pragma unroll
    for (int kk = 0; kk < 2; ++kk) {
      offA[m][kk] = ra * 64 + ((kk * 4 + lu) ^ (ra & 7)) * 8;
      offB[m][kk] = rb * 64 + ((kk * 4 + lu) ^ (rb & 7)) * 8;
    }
  }

  for (int k0 = 0; k0 < K; k0 += 64) {
    #pragma unroll
    for (int j = 0; j < 4; ++j) {
      int c = j * 256 + tid;          // chunk of 8 f16; dest stays base + lane*16B
      int row = c >> 3, p = c & 7;
      int su = p ^ (row & 7);         // pre-swizzled source -> swizzled LDS layout
      gload16(&sA[c * 8], A  + (size_t)(mBase + row) * K + k0 + su * 8);
      gload16(&sB[c * 8], Bt + (size_t)(nBase + row) * K + k0 + su * 8);
    }
    __syncthreads();
    #pragma unroll
    for (int kk = 0; kk < 2; ++kk) {
      f16x8 af[4], bf[4];
      #pragma unroll
      for (int m = 0; m < 4; ++m) af[m] = *(const f16x8*)&sA[offA[m][kk]];
      #pragma unroll
      for (int n = 0; n < 4; ++n) bf[n] = *(const f16x8*)&sB[offB[n][kk]];
      #pragma unroll
      for (int m = 0; m < 4; ++m)
        #pragma unroll
        for (int n = 0; n < 4; ++n)
          acc[m][n] = __builtin_amdgcn_mfma_f32_16x16x32_f16(af[m], bf[n], acc[m][n], 0, 0, 0);
    }
    __syncthreads();
  }

  // epilogue: stage 32x128 f16 quadrants in LDS, write coalesced f16x8
  const int rq = (lane >> 4) * 4;
  f16* sOut = sA;
  const bool isZ = (MODE == 1) && (nBase >= DI);
  f16* dst = (MODE == 0) ? O0 : (isZ ? O1 : O0);
  const int ncols = (MODE == 0) ? DM : DI;
  const int cb = isZ ? (nBase - DI) : nBase;
  #pragma unroll
  for (int m = 0; m < 4; ++m) {
    #pragma unroll
    for (int n = 0; n < 4; ++n)
      #pragma unroll
      for (int r = 0; r < 4; ++r)
        sOut[(wr * 16 + rq + r) * 128 + wc * 64 + n * 16 + lr] = (f16)acc[m][n][r];
    __syncthreads();
    #pragma unroll
    for (int q = 0; q < 2; ++q) {
      int cidx = q * 256 + tid;
      int orow = cidx >> 4;
      int ocol = (cidx & 15) * 8;
      int grow = mBase + (orow >> 4) * 64 + m * 16 + (orow & 15);
      f16x8 v = *(const f16x8*)&sOut[orow * 128 + ocol];
      *(f16x8*)&dst[(size_t)grow * ncols + cb + ocol] = v;
    }
    __syncthreads();
  }
}

// ---------------- depthwise causal conv (w=4) + SiLU + chunked local scan ----------------
// grid: (DI/512, NCH, BSZ), block 256, 2 d per thread. Xi f16 in; Hl f16, L fp32 out.
__global__ __launch_bounds__(256) void conv_scan(
    const f16* __restrict__ Xi, const float* __restrict__ convW, const float* __restrict__ convB,
    f16* __restrict__ Hl, float* __restrict__ L)
{
  const int tid = threadIdx.x;
  const int d0 = (blockIdx.x * 256 + tid) * 2;
  const int ch = blockIdx.y;
  const int b  = blockIdx.z;
  const int t0 = ch * CHUNK;

  float w0[2], w1[2], w2[2], w3[2], cb[2];
  #pragma unroll
  for (int i = 0; i < 2; ++i) {
    float4 wv = ((const float4*)convW)[d0 + i];
    w0[i] = wv.x; w1[i] = wv.y; w2[i] = wv.z; w3[i] = wv.w;
    cb[i] = convB[d0 + i];
  }

  auto loadrow = [&](int t, float* dst) {
    if (t < 0) { dst[0] = dst[1] = 0.f; return; }
    f16x2 v = *(const f16x2*)&Xi[((size_t)(b * SLEN + t)) * DI + d0];
    dst[0] = (float)v.x; dst[1] = (float)v.y;
  };

  float xm3[2], xm2[2], xm1[2];
  loadrow(t0 - 3, xm3); loadrow(t0 - 2, xm2); loadrow(t0 - 1, xm1);

  float h[2] = {0.f, 0.f};
  for (int t = 0; t < CHUNK; ++t) {
    const size_t ro = ((size_t)(b * SLEN + t0 + t)) * DI + d0;
    f16x2 xv = *(const f16x2*)&Xi[ro];
    float xt[2] = {(float)xv.x, (float)xv.y};
    #pragma unroll
    for (int i = 0; i < 2; ++i) {
      float c = cb[i] + w0[i]*xm3[i] + w1[i]*xm2[i] + w2[i]*xm1[i] + w3[i]*xt[i];
      float xc = silu_f(c);
      h[i] = DECAYF * h[i] + xc;
    }
    f16x2 hho = {(f16)h[0], (f16)h[1]};
    *(f16x2*)&Hl[ro] = hho;
    #pragma unroll
    for (int i = 0; i < 2; ++i) { xm3[i] = xm2[i]; xm2[i] = xm1[i]; xm1[i] = xt[i]; }
  }
  float2 lo = {h[0], h[1]};
  *(float2*)&L[((size_t)(b * NCH + ch)) * DI + d0] = lo;
}

// ---------------- sequential chunk-carry (8-wide batched loads), f16 output ----------------
__global__ void carry_scan(const float* __restrict__ L, f16* __restrict__ Carry) {
  int i = blockIdx.x * blockDim.x + threadIdx.x;  // 8192
  int b = i >> 11, d = i & (DI - 1);
  float dp = 1.f;
  #pragma unroll
  for (int k = 0; k < CHUNK; ++k) dp *= DECAYF;
  float c = 0.f;
  for (int ch0 = 0; ch0 < NCH; ch0 += 8) {
    float lv[8];
    #pragma unroll
    for (int k = 0; k < 8; ++k)
      lv[k] = L[((size_t)(b * NCH + ch0 + k)) * DI + d];
    #pragma unroll
    for (int k = 0; k < 8; ++k) {
      c = dp * c + lv[k];
      Carry[((size_t)(b * NCH + ch0 + k)) * DI + d] = (f16)c;
    }
  }
}

// ---------------- s_C[m][n] = sum_d silu(conv(Xi))[m,d] * W_x[16+n, d] (wave per row) ----
// recomputes conv+silu from f16 Xi directly (no Xc buffer)
__global__ __launch_bounds__(256) void sc_gemm(
    const f16* __restrict__ Xi, const float* __restrict__ convW, const float* __restrict__ convB,
    const float* __restrict__ Wx, float* __restrict__ sC)
{
  const int m = blockIdx.x * 4 + (threadIdx.x >> 6);
  const int lane = threadIdx.x & 63;
  const int b = m >> 11, t = m & (SLEN - 1);
  const f16* rowt = Xi + ((size_t)(b * SLEN + t)) * DI;

  float acc[16];
  #pragma unroll
  for (int n = 0; n < 16; ++n) acc[n] = 0.f;

  #pragma unroll
  for (int it = 0; it < DI / 256; ++it) {
    int d = it * 256 + lane * 4;
    f16x4 zz = {(f16)0, (f16)0, (f16)0, (f16)0};
    f16x4 x0 = *(const f16x4*)&rowt[d];
    f16x4 x1 = (t >= 1) ? *(const f16x4*)&rowt[d - DI]     : zz;
    f16x4 x2 = (t >= 2) ? *(const f16x4*)&rowt[d - 2 * DI] : zz;
    f16x4 x3 = (t >= 3) ? *(const f16x4*)&rowt[d - 3 * DI] : zz;
    float xc[4];
    #pragma unroll
    for (int i = 0; i < 4; ++i) {
      float4 wv = ((const float4*)convW)[d + i];
      float c = convB[d + i] + wv.x * (float)x3[i] + wv.y * (float)x2[i]
                             + wv.z * (float)x1[i] + wv.w * (float)x0[i];
      xc[i] = silu_f(c);
    }
    #pragma unroll
    for (int n = 0; n < 16; ++n) {
      float4 wv = *(const float4*)&Wx[(size_t)(16 + n) * DI + d];
      acc[n] += xc[0] * wv.x + xc[1] * wv.y + xc[2] * wv.z + xc[3] * wv.w;
    }
  }
  #pragma unroll
  for (int n = 0; n < 16; ++n) {
    #pragma unroll
    for (int off = 32; off > 0; off >>= 1) acc[n] += __shfl_xor(acc[n], off);
  }
  if (lane == 0) {
    #pragma unroll
    for (int n = 0; n < 16; ++n) sC[m * 16 + n] = acc[n];
  }
}

// ---------------- Y = (Hl + coef*Carry) * (sC·expBT) * silu(Z) ; f16 out ----------------
__global__ __launch_bounds__(256) void ew_y(
    const f16* __restrict__ Hl, const f16* __restrict__ Zs,
    const float* __restrict__ sC, const float* __restrict__ expBT,
    const f16* __restrict__ Carry, f16* __restrict__ Y)
{
  const int r = threadIdx.x >> 6, lane = threadIdx.x & 63;
  const int m = blockIdx.y * 4 + r;
  const int d0 = blockIdx.x * 512 + lane * 8;
  const int b = m >> 11, t = m & (SLEN - 1);
  const int ch = t / CHUNK, tl = t & (CHUNK - 1);

  float coef = 0.f;
  if (ch > 0) {
    coef = 1.f;
    for (int j = 0; j <= tl; ++j) coef *= DECAYF;  // 0.95^(tl+1), repeated-mul like ref
  }

  const float4 sc0 = *(const float4*)&sC[m * 16 + 0];
  const float4 sc1 = *(const float4*)&sC[m * 16 + 4];
  const float4 sc2 = *(const float4*)&sC[m * 16 + 8];
  const float4 sc3 = *(const float4*)&sC[m * 16 + 12];
  const float scv[16] = {sc0.x, sc0.y, sc0.z, sc0.w, sc1.x, sc1.y, sc1.z, sc1.w,
                         sc2.x, sc2.y, sc2.z, sc2.w, sc3.x, sc3.y, sc3.z, sc3.w};

  const size_t ro = (size_t)m * DI + d0;
  f16x8 hvv = *(const f16x8*)&Hl[ro];
  f16x8 zvv = *(const f16x8*)&Zs[ro];
  float hv[8], zv[8], ca[8];
  #pragma unroll
  for (int i = 0; i < 8; ++i) {
    hv[i] = (float)hvv[i];
    zv[i] = silu_f((float)zvv[i]);
    ca[i] = 0.f;
  }
  if (ch > 0) {
    const size_t co = ((size_t)(b * NCH + ch - 1)) * DI + d0;
    f16x8 cv = *(const f16x8*)&Carry[co];
    #pragma unroll
    for (int i = 0; i < 8; ++i) ca[i] = (float)cv[i];
  }

  float cp[8] = {0.f, 0.f, 0.f, 0.f, 0.f, 0.f, 0.f, 0.f};
  #pragma unroll
  for (int n = 0; n < 16; ++n) {
    float4 e0 = *(const float4*)&expBT[(size_t)n * DI + d0];
    float4 e1 = *(const float4*)&expBT[(size_t)n * DI + d0 + 4];
    cp[0] += scv[n] * e0.x; cp[1] += scv[n] * e0.y; cp[2] += scv[n] * e0.z; cp[3] += scv[n] * e0.w;
    cp[4] += scv[n] * e1.x; cp[5] += scv[n] * e1.y; cp[6] += scv[n] * e1.z; cp[7] += scv[n] * e1.w;
  }

  f16x8 o;
  #pragma unroll
  for (int i = 0; i < 8; ++i) {
    float y = (hv[i] + coef * ca[i]) * cp[i] * zv[i];
    o[i] = (f16)y;
  }
  *(f16x8*)&Y[ro] = o;
}

// ---------------- residual + LayerNorm (row = 1024), G is f16 ----------------
__global__ __launch_bounds__(256) void ln_res(const f16* __restrict__ G, const float* __restrict__ x,
                                              const float* __restrict__ lng, const float* __restrict__ lnb,
                                              float* __restrict__ out) {
  const int m = blockIdx.x;
  const int tid = threadIdx.x;
  f16x4 gv4 = ((const f16x4*)(G + (size_t)m * DM))[tid];
  float4 xv = ((const float4*)(x + (size_t)m * DM))[tid];
  float4 rv = {(float)gv4.x + xv.x, (float)gv4.y + xv.y, (float)gv4.z + xv.z, (float)gv4.w + xv.w};
  float s = rv.x + rv.y + rv.z + rv.w;
  float s2 = rv.x * rv.x + rv.y * rv.y + rv.z * rv.z + rv.w * rv.w;
  #pragma unroll
  for (int off = 32; off > 0; off >>= 1) {
    s += __shfl_xor(s, off);
    s2 += __shfl_xor(s2, off);
  }
  __shared__ float ps[8];
  const int w = tid >> 6;
  if ((tid & 63) == 0) { ps[w] = s; ps[w + 4] = s2; }
  __syncthreads();
  float S = ps[0] + ps[1] + ps[2] + ps[3];
  float S2 = ps[4] + ps[5] + ps[6] + ps[7];
  float mu = S * (1.f / DM);
  float var = S2 * (1.f / DM) - mu * mu;
  float rs = rsqrtf(var + 1e-5f);
  float4 gg = ((const float4*)lng)[tid];
  float4 bb = ((const float4*)lnb)[tid];
  float4 ov = {(rv.x - mu) * rs * gg.x + bb.x, (rv.y - mu) * rs * gg.y + bb.y,
               (rv.z - mu) * rs * gg.z + bb.z, (rv.w - mu) * rs * gg.w + bb.w};
  ((float4*)(out + (size_t)m * DM))[tid] = ov;
}

extern "C" void kernel_launch(void* const* d_in, const int* in_sizes, int n_in,
                              void* d_out, int out_size, void* d_ws, size_t ws_size,
                              hipStream_t stream) {
  const float* x      = (const float*)d_in[0];
  const float* W_in   = (const float*)d_in[1];
  const float* conv_w = (const float*)d_in[2];
  const float* conv_b = (const float*)d_in[3];
  const float* W_x    = (const float*)d_in[4];
  const float* B_log  = (const float*)d_in[5];
  const float* W_out  = (const float*)d_in[6];
  const float* ln_g   = (const float*)d_in[7];
  const float* ln_b   = (const float*)d_in[8];
  float* out = (float*)d_out;

  char* ws = (char*)d_ws;
  // Region map (MB offsets, peak ~145MB):
  //  [0,32)    Xi f16  -> dead after sc_gemm -> Yp f16 [0,32)
  //  [32,64)   Zs f16 (raw z)
  //  [64,96)   Hl f16
  //  [96,112)  A1 f16 (x)
  //  [112,120) B1 f16 (W_in)
  //  [120,124) W2 f16 (W_out)
  //  [124,140) G f16
  //  [140,142) L fp32 ; [142,143) Carry f16 ; [143,143.5) sC ; [144,..) expBT
  f16*   Xi  = (f16*)(ws + 0);
  f16*   Yp  = (f16*)(ws + 0);
  f16*   Zs  = (f16*)(ws + 32 * MB);
  f16*   Hl  = (f16*)(ws + 64 * MB);
  f16*   A1  = (f16*)(ws + 96 * MB);
  f16*   B1  = (f16*)(ws + 112 * MB);
  f16*   W2  = (f16*)(ws + 120 * MB);
  f16*   G   = (f16*)(ws + 124 * MB);
  float* L     = (float*)(ws + 140 * MB);
  f16*   Carry = (f16*)(ws + 142 * MB);
  float* sC    = (float*)(ws + 143 * MB);
  float* expBT = (float*)(ws + 144 * MB);

  cvt_all<<<(NX4 + NWI4 + NWO4 + NE4) / 256, 256, 0, stream>>>(
      x, W_in, W_out, B_log, A1, B1, W2, expBT);

  // GEMM1: [8192 x 4096] = A1[8192 x 1024] * B1[4096 x 1024]^T -> Xi f16, Z raw f16
  gemm_bt<1><<<dim3(2 * DI / 128, MROWS / 128), 256, 0, stream>>>(A1, B1, DM, Xi, Zs);

  conv_scan<<<dim3(DI / 512, NCH, BSZ), 256, 0, stream>>>(Xi, conv_w, conv_b, Hl, L);
  carry_scan<<<(BSZ * DI) / 256, 256, 0, stream>>>(L, Carry);
  sc_gemm<<<MROWS / 4, 256, 0, stream>>>(Xi, conv_w, conv_b, W_x, sC);
  ew_y<<<dim3(DI / 512, MROWS / 4), 256, 0, stream>>>(Hl, Zs, sC, expBT, Carry, Yp);

  // GEMM2: [8192 x 1024] = Yp[8192 x 2048] * W2[1024 x 2048]^T -> G f16
  gemm_bt<0><<<dim3(DM / 128, MROWS / 128), 256, 0, stream>>>(Yp, W2, DI, G, nullptr);

  ln_res<<<MROWS, 256, 0, stream>>>(G, x, ln_g, ln_b, out);
}

// Round 8
// 250.511 us; speedup vs baseline: 1.7161x; 1.7161x over previous
//
#include <hip/hip_runtime.h>
#include <hip/hip_bf16.h>
#include <stdint.h>

#define DM   1024
#define DI   2048
#define NST  16
#define BSZ  4
#define SLEN 2048
#define MROWS (BSZ*SLEN)   // 8192
#define CHUNK 32
#define NCH  (SLEN/CHUNK)  // 64
#define DECAYF 0.95f
#define MB (size_t)1048576

typedef _Float16 f16;
typedef __attribute__((ext_vector_type(2))) _Float16 f16x2;
typedef __attribute__((ext_vector_type(4))) _Float16 f16x4;
typedef __attribute__((ext_vector_type(8))) _Float16 f16x8;
typedef __attribute__((ext_vector_type(4))) float f32x4;

__device__ __forceinline__ float silu_f(float v) { return v / (1.f + __expf(-v)); }

__device__ __forceinline__ void gload16(const f16* lds, const f16* g) {
  __builtin_amdgcn_global_load_lds((const __attribute__((address_space(1))) void*)g,
                                   (__attribute__((address_space(3))) void*)lds, 16, 0, 0);
}

// ---- fused preprocessing: x->A1, W_in->B1, W_out->W2, W_x[16:32)->WxC f16, B_log->expBT f16 ----
#define NX4  (MROWS * DM / 4)          // 2,097,152
#define NWI4 (2 * DI * DM / 4)         // 1,048,576
#define NWO4 (DM * DI / 4)             // 524,288
#define NWX4 (NST * DI / 4)            // 8,192
#define NE4  (NST * DI / 4)            // 8,192
__global__ __launch_bounds__(256) void cvt_all(
    const float* __restrict__ x, const float* __restrict__ wi, const float* __restrict__ wo,
    const float* __restrict__ Wx, const float* __restrict__ B_log,
    f16* __restrict__ A1, f16* __restrict__ B1, f16* __restrict__ W2,
    f16* __restrict__ WxC, f16* __restrict__ expBT)
{
  int i = blockIdx.x * 256 + threadIdx.x;
  if (i < NX4 + NWI4 + NWO4 + NWX4) {
    const float* src; f16* dst; int j;
    if (i < NX4)                     { src = x;  dst = A1; j = i; }
    else if (i < NX4 + NWI4)         { src = wi; dst = B1; j = i - NX4; }
    else if (i < NX4 + NWI4 + NWO4)  { src = wo; dst = W2; j = i - NX4 - NWI4; }
    else                             { src = Wx + (size_t)NST * DI; dst = WxC; j = i - NX4 - NWI4 - NWO4; }
    float4 v = ((const float4*)src)[j];
    f16x4 o = {(f16)v.x, (f16)v.y, (f16)v.z, (f16)v.w};
    ((f16x4*)dst)[j] = o;
  } else {
    int j = i - NX4 - NWI4 - NWO4 - NWX4;  // [0, NE4)
    int base = j * 4;                      // element index n*DI+d
    int n = base >> 11, d = base & (DI - 1);
    f16x4 o = {(f16)__expf(B_log[(d + 0) * NST + n]), (f16)__expf(B_log[(d + 1) * NST + n]),
               (f16)__expf(B_log[(d + 2) * NST + n]), (f16)__expf(B_log[(d + 3) * NST + n])};
    ((f16x4*)expBT)[j] = o;
  }
}

// ---------------- fp16 MFMA GEMM, BK=64, XOR-swizzled LDS, LDS-staged f16 epilogue ----------
// MODE 1: cols < DI -> O0 = Xi (f16), cols >= DI -> O1 = Z raw (f16). MODE 0: O0 = G (f16).
template<int MODE>
__global__ __launch_bounds__(256) void gemm_bt(
    const f16* __restrict__ A, const f16* __restrict__ Bt,
    int K, f16* __restrict__ O0, f16* __restrict__ O1)
{
  __shared__ __align__(16) f16 sA[128 * 64];
  __shared__ __align__(16) f16 sB[128 * 64];
  const int tid  = threadIdx.x;
  const int lane = tid & 63;
  const int w    = tid >> 6;
  const int wr   = w >> 1, wc = w & 1;

  // bijective XCD swizzle (nwg % 8 == 0 for both GEMMs)
  const int nwg  = gridDim.x * gridDim.y;
  int wgid = blockIdx.y * gridDim.x + blockIdx.x;
  wgid = (wgid & 7) * (nwg >> 3) + (wgid >> 3);
  const int bx = wgid % gridDim.x;
  const int by = wgid / gridDim.x;

  const int mBase = by * 128;
  const int nBase = bx * 128;
  const int lr = lane & 15;
  const int lu = lane >> 4;   // k-unit (8 f16) within 32-k window

  f32x4 acc[4][4];
  #pragma unroll
  for (int m = 0; m < 4; ++m)
    #pragma unroll
    for (int n = 0; n < 4; ++n)
      acc[m][n] = (f32x4){0.f, 0.f, 0.f, 0.f};

  // ds_read offsets (f16 units), loop-invariant
  int offA[4][2], offB[4][2];
  #pragma unroll
  for (int m = 0; m < 4; ++m) {
    int ra = wr * 64 + m * 16 + lr;
    int rb = wc * 64 + m * 16 + lr;
    #pragma unroll
    for (int kk = 0; kk < 2; ++kk) {
      offA[m][kk] = ra * 64 + ((kk * 4 + lu) ^ (ra & 7)) * 8;
      offB[m][kk] = rb * 64 + ((kk * 4 + lu) ^ (rb & 7)) * 8;
    }
  }

  for (int k0 = 0; k0 < K; k0 += 64) {
    #pragma unroll
    for (int j = 0; j < 4; ++j) {
      int c = j * 256 + tid;          // chunk of 8 f16; dest stays base + lane*16B
      int row = c >> 3, p = c & 7;
      int su = p ^ (row & 7);         // pre-swizzled source -> swizzled LDS layout
      gload16(&sA[c * 8], A  + (size_t)(mBase + row) * K + k0 + su * 8);
      gload16(&sB[c * 8], Bt + (size_t)(nBase + row) * K + k0 + su * 8);
    }
    __syncthreads();
    #pragma unroll
    for (int kk = 0; kk < 2; ++kk) {
      f16x8 af[4], bf[4];
      #pragma unroll
      for (int m = 0; m < 4; ++m) af[m] = *(const f16x8*)&sA[offA[m][kk]];
      #pragma unroll
      for (int n = 0; n < 4; ++n) bf[n] = *(const f16x8*)&sB[offB[n][kk]];
      #pragma unroll
      for (int m = 0; m < 4; ++m)
        #pragma unroll
        for (int n = 0; n < 4; ++n)
          acc[m][n] = __builtin_amdgcn_mfma_f32_16x16x32_f16(af[m], bf[n], acc[m][n], 0, 0, 0);
    }
    __syncthreads();
  }

  // epilogue: stage 32x128 f16 quadrants in LDS, write coalesced f16x8
  const int rq = (lane >> 4) * 4;
  f16* sOut = sA;
  const bool isZ = (MODE == 1) && (nBase >= DI);
  f16* dst = (MODE == 0) ? O0 : (isZ ? O1 : O0);
  const int ncols = (MODE == 0) ? DM : DI;
  const int cb = isZ ? (nBase - DI) : nBase;
  #pragma unroll
  for (int m = 0; m < 4; ++m) {
    #pragma unroll
    for (int n = 0; n < 4; ++n)
      #pragma unroll
      for (int r = 0; r < 4; ++r)
        sOut[(wr * 16 + rq + r) * 128 + wc * 64 + n * 16 + lr] = (f16)acc[m][n][r];
    __syncthreads();
    #pragma unroll
    for (int q = 0; q < 2; ++q) {
      int cidx = q * 256 + tid;
      int orow = cidx >> 4;
      int ocol = (cidx & 15) * 8;
      int grow = mBase + (orow >> 4) * 64 + m * 16 + (orow & 15);
      f16x8 v = *(const f16x8*)&sOut[orow * 128 + ocol];
      *(f16x8*)&dst[(size_t)grow * ncols + cb + ocol] = v;
    }
    __syncthreads();
  }
}

// ---------------- depthwise causal conv (w=4) + SiLU + chunked local scan ----------------
// grid: (DI/512, NCH, BSZ), block 256, 2 d per thread. Xi f16 in; Xc,Hl f16 out.
__global__ __launch_bounds__(256) void conv_scan(
    const f16* __restrict__ Xi, const float* __restrict__ convW, const float* __restrict__ convB,
    f16* __restrict__ Xc, f16* __restrict__ Hl, float* __restrict__ L)
{
  const int tid = threadIdx.x;
  const int d0 = (blockIdx.x * 256 + tid) * 2;
  const int ch = blockIdx.y;
  const int b  = blockIdx.z;
  const int t0 = ch * CHUNK;

  float w0[2], w1[2], w2[2], w3[2], cb[2];
  #pragma unroll
  for (int i = 0; i < 2; ++i) {
    float4 wv = ((const float4*)convW)[d0 + i];
    w0[i] = wv.x; w1[i] = wv.y; w2[i] = wv.z; w3[i] = wv.w;
    cb[i] = convB[d0 + i];
  }

  auto loadrow = [&](int t, float* dst) {
    if (t < 0) { dst[0] = dst[1] = 0.f; return; }
    f16x2 v = *(const f16x2*)&Xi[((size_t)(b * SLEN + t)) * DI + d0];
    dst[0] = (float)v.x; dst[1] = (float)v.y;
  };

  float xm3[2], xm2[2], xm1[2];
  loadrow(t0 - 3, xm3); loadrow(t0 - 2, xm2); loadrow(t0 - 1, xm1);

  float h[2] = {0.f, 0.f};
  for (int t = 0; t < CHUNK; ++t) {
    const size_t ro = ((size_t)(b * SLEN + t0 + t)) * DI + d0;
    f16x2 xv = *(const f16x2*)&Xi[ro];
    float xt[2] = {(float)xv.x, (float)xv.y};
    float xc[2];
    #pragma unroll
    for (int i = 0; i < 2; ++i) {
      float c = cb[i] + w0[i]*xm3[i] + w1[i]*xm2[i] + w2[i]*xm1[i] + w3[i]*xt[i];
      xc[i] = silu_f(c);
      h[i] = DECAYF * h[i] + xc[i];
    }
    f16x2 xco = {(f16)xc[0], (f16)xc[1]};
    f16x2 hho = {(f16)h[0], (f16)h[1]};
    *(f16x2*)&Xc[ro] = xco;
    *(f16x2*)&Hl[ro] = hho;
    #pragma unroll
    for (int i = 0; i < 2; ++i) { xm3[i] = xm2[i]; xm2[i] = xm1[i]; xm1[i] = xt[i]; }
  }
  float2 lo = {h[0], h[1]};
  *(float2*)&L[((size_t)(b * NCH + ch)) * DI + d0] = lo;
}

// ---------------- sequential chunk-carry (8-wide batched loads), f16 output ----------------
__global__ void carry_scan(const float* __restrict__ L, f16* __restrict__ Carry) {
  int i = blockIdx.x * blockDim.x + threadIdx.x;  // 8192
  int b = i >> 11, d = i & (DI - 1);
  float dp = 1.f;
  #pragma unroll
  for (int k = 0; k < CHUNK; ++k) dp *= DECAYF;
  float c = 0.f;
  for (int ch0 = 0; ch0 < NCH; ch0 += 8) {
    float lv[8];
    #pragma unroll
    for (int k = 0; k < 8; ++k)
      lv[k] = L[((size_t)(b * NCH + ch0 + k)) * DI + d];
    #pragma unroll
    for (int k = 0; k < 8; ++k) {
      c = dp * c + lv[k];
      Carry[((size_t)(b * NCH + ch0 + k)) * DI + d] = (f16)c;
    }
  }
}

// ---------------- s_C[m][n] = sum_d Xc[m,d] * WxC[n, d]  (wave per row, f16 inputs) ----------
__global__ __launch_bounds__(256) void sc_gemm(const f16* __restrict__ Xc, const f16* __restrict__ WxC,
                                               float* __restrict__ sC) {
  const int m = blockIdx.x * 4 + (threadIdx.x >> 6);
  const int lane = threadIdx.x & 63;
  float acc[16];
  #pragma unroll
  for (int n = 0; n < 16; ++n) acc[n] = 0.f;
  #pragma unroll
  for (int it = 0; it < DI / 256; ++it) {
    int d = it * 256 + lane * 4;
    f16x4 xv = *(const f16x4*)&Xc[(size_t)m * DI + d];
    float x0 = (float)xv.x, x1 = (float)xv.y, x2 = (float)xv.z, x3 = (float)xv.w;
    #pragma unroll
    for (int n = 0; n < 16; ++n) {
      f16x4 wv = *(const f16x4*)&WxC[(size_t)n * DI + d];
      acc[n] += x0 * (float)wv.x + x1 * (float)wv.y + x2 * (float)wv.z + x3 * (float)wv.w;
    }
  }
  #pragma unroll
  for (int n = 0; n < 16; ++n) {
    #pragma unroll
    for (int off = 32; off > 0; off >>= 1) acc[n] += __shfl_xor(acc[n], off);
  }
  if (lane == 0) {
    #pragma unroll
    for (int n = 0; n < 16; ++n) sC[m * 16 + n] = acc[n];
  }
}

// ---------------- Y = (Hl + coef*Carry) * (sC·expBT) * silu(Z) ; f16 out ----------------
__global__ __launch_bounds__(256) void ew_y(
    const f16* __restrict__ Hl, const f16* __restrict__ Zs,
    const float* __restrict__ sC, const f16* __restrict__ expBT,
    const f16* __restrict__ Carry, f16* __restrict__ Y)
{
  const int r = threadIdx.x >> 6, lane = threadIdx.x & 63;
  const int m = blockIdx.y * 4 + r;
  const int d0 = blockIdx.x * 512 + lane * 8;
  const int b = m >> 11, t = m & (SLEN - 1);
  const int ch = t / CHUNK, tl = t & (CHUNK - 1);

  float coef = 0.f;
  if (ch > 0) {
    coef = 1.f;
    for (int j = 0; j <= tl; ++j) coef *= DECAYF;  // 0.95^(tl+1), repeated-mul like ref
  }

  const float4 sc0 = *(const float4*)&sC[m * 16 + 0];
  const float4 sc1 = *(const float4*)&sC[m * 16 + 4];
  const float4 sc2 = *(const float4*)&sC[m * 16 + 8];
  const float4 sc3 = *(const float4*)&sC[m * 16 + 12];
  const float scv[16] = {sc0.x, sc0.y, sc0.z, sc0.w, sc1.x, sc1.y, sc1.z, sc1.w,
                         sc2.x, sc2.y, sc2.z, sc2.w, sc3.x, sc3.y, sc3.z, sc3.w};

  const size_t ro = (size_t)m * DI + d0;
  f16x8 hvv = *(const f16x8*)&Hl[ro];
  f16x8 zvv = *(const f16x8*)&Zs[ro];
  float hv[8], zv[8], ca[8];
  #pragma unroll
  for (int i = 0; i < 8; ++i) {
    hv[i] = (float)hvv[i];
    zv[i] = silu_f((float)zvv[i]);
    ca[i] = 0.f;
  }
  if (ch > 0) {
    const size_t co = ((size_t)(b * NCH + ch - 1)) * DI + d0;
    f16x8 cv = *(const f16x8*)&Carry[co];
    #pragma unroll
    for (int i = 0; i < 8; ++i) ca[i] = (float)cv[i];
  }

  float cp[8] = {0.f, 0.f, 0.f, 0.f, 0.f, 0.f, 0.f, 0.f};
  #pragma unroll
  for (int n = 0; n < 16; ++n) {
    f16x8 ev = *(const f16x8*)&expBT[(size_t)n * DI + d0];
    #pragma unroll
    for (int i = 0; i < 8; ++i) cp[i] += scv[n] * (float)ev[i];
  }

  f16x8 o;
  #pragma unroll
  for (int i = 0; i < 8; ++i) {
    float y = (hv[i] + coef * ca[i]) * cp[i] * zv[i];
    o[i] = (f16)y;
  }
  *(f16x8*)&Y[ro] = o;
}

// ---------------- residual + LayerNorm (row = 1024), G is f16 ----------------
__global__ __launch_bounds__(256) void ln_res(const f16* __restrict__ G, const float* __restrict__ x,
                                              const float* __restrict__ lng, const float* __restrict__ lnb,
                                              float* __restrict__ out) {
  const int m = blockIdx.x;
  const int tid = threadIdx.x;
  f16x4 gv4 = ((const f16x4*)(G + (size_t)m * DM))[tid];
  float4 xv = ((const float4*)(x + (size_t)m * DM))[tid];
  float4 rv = {(float)gv4.x + xv.x, (float)gv4.y + xv.y, (float)gv4.z + xv.z, (float)gv4.w + xv.w};
  float s = rv.x + rv.y + rv.z + rv.w;
  float s2 = rv.x * rv.x + rv.y * rv.y + rv.z * rv.z + rv.w * rv.w;
  #pragma unroll
  for (int off = 32; off > 0; off >>= 1) {
    s += __shfl_xor(s, off);
    s2 += __shfl_xor(s2, off);
  }
  __shared__ float ps[8];
  const int w = tid >> 6;
  if ((tid & 63) == 0) { ps[w] = s; ps[w + 4] = s2; }
  __syncthreads();
  float S = ps[0] + ps[1] + ps[2] + ps[3];
  float S2 = ps[4] + ps[5] + ps[6] + ps[7];
  float mu = S * (1.f / DM);
  float var = S2 * (1.f / DM) - mu * mu;
  float rs = rsqrtf(var + 1e-5f);
  float4 gg = ((const float4*)lng)[tid];
  float4 bb = ((const float4*)lnb)[tid];
  float4 ov = {(rv.x - mu) * rs * gg.x + bb.x, (rv.y - mu) * rs * gg.y + bb.y,
               (rv.z - mu) * rs * gg.z + bb.z, (rv.w - mu) * rs * gg.w + bb.w};
  ((float4*)(out + (size_t)m * DM))[tid] = ov;
}

extern "C" void kernel_launch(void* const* d_in, const int* in_sizes, int n_in,
                              void* d_out, int out_size, void* d_ws, size_t ws_size,
                              hipStream_t stream) {
  const float* x      = (const float*)d_in[0];
  const float* W_in   = (const float*)d_in[1];
  const float* conv_w = (const float*)d_in[2];
  const float* conv_b = (const float*)d_in[3];
  const float* W_x    = (const float*)d_in[4];
  const float* B_log  = (const float*)d_in[5];
  const float* W_out  = (const float*)d_in[6];
  const float* ln_g   = (const float*)d_in[7];
  const float* ln_b   = (const float*)d_in[8];
  float* out = (float*)d_out;

  char* ws = (char*)d_ws;
  // Region map (MB offsets, peak ~178MB):
  //  [0,32)    Xi f16  -> dead after sc_gemm -> Yp f16 [0,32)
  //  [32,64)   Zs f16 (raw z)
  //  [64,96)   Xc f16
  //  [96,128)  Hl f16
  //  [128,144) A1 f16 (x)
  //  [144,152) B1 f16 (W_in)
  //  [152,156) W2 f16 (W_out)
  //  [156,172) G f16
  //  [172,174) L fp32 ; [174,175) Carry f16 ; [175,176) sC fp32 ;
  //  [176,..)  expBT f16 (64KB) ; [177,..) WxC f16 (64KB)
  f16*   Xi  = (f16*)(ws + 0);
  f16*   Yp  = (f16*)(ws + 0);
  f16*   Zs  = (f16*)(ws + 32 * MB);
  f16*   Xc  = (f16*)(ws + 64 * MB);
  f16*   Hl  = (f16*)(ws + 96 * MB);
  f16*   A1  = (f16*)(ws + 128 * MB);
  f16*   B1  = (f16*)(ws + 144 * MB);
  f16*   W2  = (f16*)(ws + 152 * MB);
  f16*   G   = (f16*)(ws + 156 * MB);
  float* L     = (float*)(ws + 172 * MB);
  f16*   Carry = (f16*)(ws + 174 * MB);
  float* sC    = (float*)(ws + 175 * MB);
  f16*   expBT = (f16*)(ws + 176 * MB);
  f16*   WxC   = (f16*)(ws + 177 * MB);

  cvt_all<<<(NX4 + NWI4 + NWO4 + NWX4 + NE4) / 256, 256, 0, stream>>>(
      x, W_in, W_out, W_x, B_log, A1, B1, W2, WxC, expBT);

  // GEMM1: [8192 x 4096] = A1[8192 x 1024] * B1[4096 x 1024]^T -> Xi f16, Z raw f16
  gemm_bt<1><<<dim3(2 * DI / 128, MROWS / 128), 256, 0, stream>>>(A1, B1, DM, Xi, Zs);

  conv_scan<<<dim3(DI / 512, NCH, BSZ), 256, 0, stream>>>(Xi, conv_w, conv_b, Xc, Hl, L);
  carry_scan<<<(BSZ * DI) / 256, 256, 0, stream>>>(L, Carry);
  sc_gemm<<<MROWS / 4, 256, 0, stream>>>(Xc, WxC, sC);
  ew_y<<<dim3(DI / 512, MROWS / 4), 256, 0, stream>>>(Hl, Zs, sC, expBT, Carry, Yp);

  // GEMM2: [8192 x 1024] = Yp[8192 x 2048] * W2[1024 x 2048]^T -> G f16
  gemm_bt<0><<<dim3(DM / 128, MROWS / 128), 256, 0, stream>>>(Yp, W2, DI, G, nullptr);

  ln_res<<<MROWS, 256, 0, stream>>>(G, x, ln_g, ln_b, out);
}